// Round 7
// baseline (122.912 us; speedup 1.0000x reference)
//
#include <hip/hip_runtime.h>

// Problem constants (match reference)
#define DEPTH    257     // 256 train ids + OOV
#define OUT_DIM  64
#define OOV_B    256
#define LUT_SIZE 512
#define TAB_QUADS (DEPTH * 16)   // 4112 f32x4 = 65,792 B (bucket-space table)
#define BLOCK    1024
#define GRID     512             // 2 blocks/CU (67.8 KB LDS) -> 32 waves/CU

typedef float f32x4 __attribute__((ext_vector_type(4)));

// Single fused kernel, R2 hot-loop shape, bucket-space LDS table.
// Key insight: for this problem's lut (TRAIN_IDS = range(256)),
// bucket(id) == min((unsigned)id, 256). Verified at runtime during staging;
// generic sLut fallback keeps the kernel correct for arbitrary lut inputs.
// Halving the table (513 id-rows -> 257 bucket-rows) fits 2 blocks/CU:
// 32 waves/CU to hide the id-load -> ds_read dependent chain.
__global__ __launch_bounds__(BLOCK) void onehot_fused_kernel(
        const float* __restrict__ raw_ids,
        const float* __restrict__ W,
        const int* __restrict__ lut,
        f32x4* __restrict__ out4,
        int total_quads) {
    __shared__ f32x4 sTab[TAB_QUADS];    // 65,792 B : sTab[b*16+qq] = W.T[b] quad qq
    __shared__ int   sLut[LUT_SIZE + 1]; //  2,052 B : generic fallback path
    __shared__ int   sOk;

    if (threadIdx.x == 0) sOk = 1;
    __syncthreads();

    // Stage lut + verify the identity-min structure.
    for (int k = threadIdx.x; k <= LUT_SIZE; k += BLOCK) {
        int v = (k < LUT_SIZE) ? lut[k] : OOV_B;
        sLut[k] = v;
        if (v != min(k, OOV_B)) sOk = 0;     // benign race: only 0 is written
    }
    // Stage W transposed into bucket-space quads (W is 65 KB, L2-resident).
    for (int k = threadIdx.x; k < TAB_QUADS; k += BLOCK) {
        int b  = k >> 4;                     // bucket 0..256
        int qq = k & 15;                     // quad within row
        f32x4 v;
        v.x = W[(4 * qq + 0) * DEPTH + b];
        v.y = W[(4 * qq + 1) * DEPTH + b];
        v.z = W[(4 * qq + 2) * DEPTH + b];
        v.w = W[(4 * qq + 3) * DEPTH + b];
        sTab[k] = v;
    }
    __syncthreads();

    const bool fast = (sOk != 0);            // block-uniform
    const int stride = GRID * BLOCK;         // 524,288 quads = 8 MB/step
    int j = blockIdx.x * BLOCK + threadIdx.x;
    const int q = j & 15;                    // invariant (stride % 16 == 0)

    if (fast) {
        // bucket = min((unsigned)id, 256) — one VALU op, one LDS hop.
        for (; j + 3 * stride < total_quads; j += 4 * stride) {
            int j0 = j, j1 = j + stride, j2 = j + 2 * stride, j3 = j + 3 * stride;
            float f0 = raw_ids[j0 >> 4];
            float f1 = raw_ids[j1 >> 4];
            float f2 = raw_ids[j2 >> 4];
            float f3 = raw_ids[j3 >> 4];
            unsigned u0 = min((unsigned)__float2int_rn(f0), (unsigned)OOV_B);
            unsigned u1 = min((unsigned)__float2int_rn(f1), (unsigned)OOV_B);
            unsigned u2 = min((unsigned)__float2int_rn(f2), (unsigned)OOV_B);
            unsigned u3 = min((unsigned)__float2int_rn(f3), (unsigned)OOV_B);
            f32x4 v0 = sTab[u0 * 16 + q];
            f32x4 v1 = sTab[u1 * 16 + q];
            f32x4 v2 = sTab[u2 * 16 + q];
            f32x4 v3 = sTab[u3 * 16 + q];
            __builtin_nontemporal_store(v0, &out4[j0]);
            __builtin_nontemporal_store(v1, &out4[j1]);
            __builtin_nontemporal_store(v2, &out4[j2]);
            __builtin_nontemporal_store(v3, &out4[j3]);
        }
        for (; j < total_quads; j += stride) {
            unsigned u = min((unsigned)__float2int_rn(raw_ids[j >> 4]),
                             (unsigned)OOV_B);
            __builtin_nontemporal_store(sTab[u * 16 + q], &out4[j]);
        }
    } else {
        // Generic path: id -> sLut -> clamped bucket -> sTab.
        for (; j + 3 * stride < total_quads; j += 4 * stride) {
            int j0 = j, j1 = j + stride, j2 = j + 2 * stride, j3 = j + 3 * stride;
            float f0 = raw_ids[j0 >> 4];
            float f1 = raw_ids[j1 >> 4];
            float f2 = raw_ids[j2 >> 4];
            float f3 = raw_ids[j3 >> 4];
            unsigned i0 = min((unsigned)__float2int_rn(f0), (unsigned)LUT_SIZE);
            unsigned i1 = min((unsigned)__float2int_rn(f1), (unsigned)LUT_SIZE);
            unsigned i2 = min((unsigned)__float2int_rn(f2), (unsigned)LUT_SIZE);
            unsigned i3 = min((unsigned)__float2int_rn(f3), (unsigned)LUT_SIZE);
            unsigned b0 = min((unsigned)sLut[i0], (unsigned)OOV_B);
            unsigned b1 = min((unsigned)sLut[i1], (unsigned)OOV_B);
            unsigned b2 = min((unsigned)sLut[i2], (unsigned)OOV_B);
            unsigned b3 = min((unsigned)sLut[i3], (unsigned)OOV_B);
            f32x4 v0 = sTab[b0 * 16 + q];
            f32x4 v1 = sTab[b1 * 16 + q];
            f32x4 v2 = sTab[b2 * 16 + q];
            f32x4 v3 = sTab[b3 * 16 + q];
            __builtin_nontemporal_store(v0, &out4[j0]);
            __builtin_nontemporal_store(v1, &out4[j1]);
            __builtin_nontemporal_store(v2, &out4[j2]);
            __builtin_nontemporal_store(v3, &out4[j3]);
        }
        for (; j < total_quads; j += stride) {
            unsigned i = min((unsigned)__float2int_rn(raw_ids[j >> 4]),
                             (unsigned)LUT_SIZE);
            unsigned b = min((unsigned)sLut[i], (unsigned)OOV_B);
            __builtin_nontemporal_store(sTab[b * 16 + q], &out4[j]);
        }
    }
}

extern "C" void kernel_launch(void* const* d_in, const int* in_sizes, int n_in,
                              void* d_out, int out_size, void* d_ws,
                              size_t ws_size, hipStream_t stream) {
    const float* raw_ids = (const float*)d_in[0];   // [N] f32 (integral values)
    const float* W       = (const float*)d_in[1];   // [64][257] f32
    const int*   lut     = (const int*)d_in[2];     // [512] i32
    float*       out     = (float*)d_out;           // [N][64] f32
    (void)d_ws; (void)ws_size;

    const int n = in_sizes[0];                      // 2,097,152
    const int total_quads = n * (OUT_DIM / 4);      // 33,554,432

    onehot_fused_kernel<<<GRID, BLOCK, 0, stream>>>(
        raw_ids, W, lut, (f32x4*)out, total_quads);
}

// Round 8
// 106.040 us; speedup vs baseline: 1.1591x; 1.1591x over previous
//
#include <hip/hip_runtime.h>

// Problem constants (match reference)
#define DEPTH     257    // 256 train ids + OOV
#define OUT_DIM   64
#define OOV_B     256
#define LUT_SIZE  512
#define TAB_QUADS (DEPTH * 16)     // 4112 f32x4 = 65,792 B (bucket-space table)
#define BLOCK     1024
#define GRID      256              // 1 block/CU; 2-blocks/CU regressed (R3/R7)
#define STEPS     128              // grid steps for N = 2M: total_quads/(GRID*BLOCK)
#define IDS_PER_BLK (STEPS * 64)   // 8192 ids = 32 KB staged per block

typedef float f32x4 __attribute__((ext_vector_type(4)));

// Hot loop is a PURE WRITE STREAM: this block's 8192 ids are staged into LDS
// up front (coalesced, one-time), the 257-row W.T bucket table likewise.
// Tests the mixed-read/write-turnaround theory for the 110-vs-83us gap:
// fill kernels (write-only) hit 6.6 TB/s; our loop now matches their
// global-traffic shape exactly.
// bucket(id) == min((unsigned)id,256) for this lut (verified at runtime;
// generic sLut path kept for arbitrary lut correctness).
__global__ __launch_bounds__(BLOCK) void onehot_purewrite_kernel(
        const float* __restrict__ raw_ids,
        const float* __restrict__ W,
        const int* __restrict__ lut,
        f32x4* __restrict__ out4,
        int total_quads) {
    __shared__ f32x4 sTab[TAB_QUADS];        // 65,792 B
    __shared__ float sIds[IDS_PER_BLK];      // 32,768 B
    __shared__ int   sLut[LUT_SIZE + 1];     //  2,052 B
    __shared__ int   sOk;

    if (threadIdx.x == 0) sOk = 1;
    __syncthreads();

    const int fastShape = (total_quads == GRID * BLOCK * STEPS);

    // ---- stage ids (coalesced float4; 2 loads/thread) ----
    if (fastShape) {
        const float4* raw4 = (const float4*)raw_ids;
        float4* sIds4 = (float4*)sIds;
        #pragma unroll
        for (int i = 0; i < 2; ++i) {
            int k = threadIdx.x + i * BLOCK;         // 0..2047
            int m = k >> 4;                          // grid step 0..127
            int kk = k & 15;
            sIds4[k] = raw4[blockIdx.x * 16 + m * (GRID * 16) + kk];
        }
    }
    // ---- stage lut + verify identity-min structure ----
    for (int k = threadIdx.x; k <= LUT_SIZE; k += BLOCK) {
        int v = (k < LUT_SIZE) ? lut[k] : OOV_B;
        sLut[k] = v;
        if (v != min(k, OOV_B)) sOk = 0;             // benign race: only 0 written
    }
    // ---- stage W.T bucket table (scalar L2 gathers, one-time) ----
    for (int k = threadIdx.x; k < TAB_QUADS; k += BLOCK) {
        int b  = k >> 4;                             // bucket 0..256
        int qq = k & 15;
        f32x4 v;
        v.x = W[(4 * qq + 0) * DEPTH + b];
        v.y = W[(4 * qq + 1) * DEPTH + b];
        v.z = W[(4 * qq + 2) * DEPTH + b];
        v.w = W[(4 * qq + 3) * DEPTH + b];
        sTab[k] = v;
    }
    __syncthreads();

    const bool fast = (sOk != 0);                    // block-uniform
    const int stride = GRID * BLOCK;
    const int j0 = blockIdx.x * BLOCK + threadIdx.x;
    const int q  = j0 & 15;                          // invariant
    const int r  = threadIdx.x >> 4;                 // row-in-chunk 0..63

    if (fastShape && fast) {
        // Pure-write hot loop: LDS id (16-lane broadcast) -> min ->
        // LDS table quad -> NT store. x4 unrolled over grid steps.
        #pragma unroll 1
        for (int m = 0; m < STEPS; m += 4) {
            float f0 = sIds[(m + 0) * 64 + r];
            float f1 = sIds[(m + 1) * 64 + r];
            float f2 = sIds[(m + 2) * 64 + r];
            float f3 = sIds[(m + 3) * 64 + r];
            unsigned u0 = min((unsigned)__float2int_rn(f0), (unsigned)OOV_B);
            unsigned u1 = min((unsigned)__float2int_rn(f1), (unsigned)OOV_B);
            unsigned u2 = min((unsigned)__float2int_rn(f2), (unsigned)OOV_B);
            unsigned u3 = min((unsigned)__float2int_rn(f3), (unsigned)OOV_B);
            f32x4 v0 = sTab[u0 * 16 + q];
            f32x4 v1 = sTab[u1 * 16 + q];
            f32x4 v2 = sTab[u2 * 16 + q];
            f32x4 v3 = sTab[u3 * 16 + q];
            int j = j0 + m * stride;
            __builtin_nontemporal_store(v0, &out4[j]);
            __builtin_nontemporal_store(v1, &out4[j + stride]);
            __builtin_nontemporal_store(v2, &out4[j + 2 * stride]);
            __builtin_nontemporal_store(v3, &out4[j + 3 * stride]);
        }
    } else {
        // Generic path (any shape / any lut): ids from global, two-hop map.
        for (int j = j0; j < total_quads; j += stride) {
            unsigned i = min((unsigned)__float2int_rn(raw_ids[j >> 4]),
                             (unsigned)LUT_SIZE);
            unsigned b = min((unsigned)sLut[i], (unsigned)OOV_B);
            __builtin_nontemporal_store(sTab[b * 16 + (j & 15)], &out4[j]);
        }
    }
}

extern "C" void kernel_launch(void* const* d_in, const int* in_sizes, int n_in,
                              void* d_out, int out_size, void* d_ws,
                              size_t ws_size, hipStream_t stream) {
    const float* raw_ids = (const float*)d_in[0];   // [N] f32 (integral values)
    const float* W       = (const float*)d_in[1];   // [64][257] f32
    const int*   lut     = (const int*)d_in[2];     // [512] i32
    float*       out     = (float*)d_out;           // [N][64] f32
    (void)d_ws; (void)ws_size;

    const int n = in_sizes[0];                      // 2,097,152
    const int total_quads = n * (OUT_DIM / 4);      // 33,554,432

    onehot_purewrite_kernel<<<GRID, BLOCK, 0, stream>>>(
        raw_ids, W, lut, (f32x4*)out, total_quads);
}

// Round 9
// 105.380 us; speedup vs baseline: 1.1664x; 1.0063x over previous
//
#include <hip/hip_runtime.h>

// Problem constants (match reference)
#define DEPTH     257    // 256 train ids + OOV
#define OUT_DIM   64
#define OOV_B     256
#define LUT_SIZE  512
#define TAB_QUADS (DEPTH * 16)     // 4112 f32x4 = 65,792 B (bucket-space table)
#define BLOCK     1024
#define GRID      256              // 1 block/CU; 2-blocks/CU regressed (R3/R7)
#define STEPS     128              // grid steps for N = 2M: total_quads/(GRID*BLOCK)
#define IDS_PER_BLK (STEPS * 64)   // 8192 ids = 32 KB staged per block

typedef float f32x4 __attribute__((ext_vector_type(4)));

// R8 structure, ONE change: regular (cached) stores instead of nontemporal.
// A/B on store policy: cached stores aggregate in L2 (32 MB) and drain to
// DRAM in large bursts (the 6.76 TB/s fill kernel's mode); NT streams from
// 256 CUs may fragment DRAM scheduling. Everything else byte-identical.
__global__ __launch_bounds__(BLOCK) void onehot_purewrite_kernel(
        const float* __restrict__ raw_ids,
        const float* __restrict__ W,
        const int* __restrict__ lut,
        f32x4* __restrict__ out4,
        int total_quads) {
    __shared__ f32x4 sTab[TAB_QUADS];        // 65,792 B
    __shared__ float sIds[IDS_PER_BLK];      // 32,768 B
    __shared__ int   sLut[LUT_SIZE + 1];     //  2,052 B
    __shared__ int   sOk;

    if (threadIdx.x == 0) sOk = 1;
    __syncthreads();

    const int fastShape = (total_quads == GRID * BLOCK * STEPS);

    // ---- stage ids (coalesced float4; 2 loads/thread) ----
    if (fastShape) {
        const float4* raw4 = (const float4*)raw_ids;
        float4* sIds4 = (float4*)sIds;
        #pragma unroll
        for (int i = 0; i < 2; ++i) {
            int k = threadIdx.x + i * BLOCK;         // 0..2047
            int m = k >> 4;                          // grid step 0..127
            int kk = k & 15;
            sIds4[k] = raw4[blockIdx.x * 16 + m * (GRID * 16) + kk];
        }
    }
    // ---- stage lut + verify identity-min structure ----
    for (int k = threadIdx.x; k <= LUT_SIZE; k += BLOCK) {
        int v = (k < LUT_SIZE) ? lut[k] : OOV_B;
        sLut[k] = v;
        if (v != min(k, OOV_B)) sOk = 0;             // benign race: only 0 written
    }
    // ---- stage W.T bucket table (scalar L2 gathers, one-time) ----
    for (int k = threadIdx.x; k < TAB_QUADS; k += BLOCK) {
        int b  = k >> 4;                             // bucket 0..256
        int qq = k & 15;
        f32x4 v;
        v.x = W[(4 * qq + 0) * DEPTH + b];
        v.y = W[(4 * qq + 1) * DEPTH + b];
        v.z = W[(4 * qq + 2) * DEPTH + b];
        v.w = W[(4 * qq + 3) * DEPTH + b];
        sTab[k] = v;
    }
    __syncthreads();

    const bool fast = (sOk != 0);                    // block-uniform
    const int stride = GRID * BLOCK;
    const int j0 = blockIdx.x * BLOCK + threadIdx.x;
    const int q  = j0 & 15;                          // invariant
    const int r  = threadIdx.x >> 4;                 // row-in-chunk 0..63

    if (fastShape && fast) {
        // Pure-write hot loop: LDS id (16-lane broadcast) -> min ->
        // LDS table quad -> CACHED store. x4 unrolled over grid steps.
        #pragma unroll 1
        for (int m = 0; m < STEPS; m += 4) {
            float f0 = sIds[(m + 0) * 64 + r];
            float f1 = sIds[(m + 1) * 64 + r];
            float f2 = sIds[(m + 2) * 64 + r];
            float f3 = sIds[(m + 3) * 64 + r];
            unsigned u0 = min((unsigned)__float2int_rn(f0), (unsigned)OOV_B);
            unsigned u1 = min((unsigned)__float2int_rn(f1), (unsigned)OOV_B);
            unsigned u2 = min((unsigned)__float2int_rn(f2), (unsigned)OOV_B);
            unsigned u3 = min((unsigned)__float2int_rn(f3), (unsigned)OOV_B);
            f32x4 v0 = sTab[u0 * 16 + q];
            f32x4 v1 = sTab[u1 * 16 + q];
            f32x4 v2 = sTab[u2 * 16 + q];
            f32x4 v3 = sTab[u3 * 16 + q];
            int j = j0 + m * stride;
            out4[j]              = v0;
            out4[j + stride]     = v1;
            out4[j + 2 * stride] = v2;
            out4[j + 3 * stride] = v3;
        }
    } else {
        // Generic path (any shape / any lut): ids from global, two-hop map.
        for (int j = j0; j < total_quads; j += stride) {
            unsigned i = min((unsigned)__float2int_rn(raw_ids[j >> 4]),
                             (unsigned)LUT_SIZE);
            unsigned b = min((unsigned)sLut[i], (unsigned)OOV_B);
            out4[j] = sTab[b * 16 + (j & 15)];
        }
    }
}

extern "C" void kernel_launch(void* const* d_in, const int* in_sizes, int n_in,
                              void* d_out, int out_size, void* d_ws,
                              size_t ws_size, hipStream_t stream) {
    const float* raw_ids = (const float*)d_in[0];   // [N] f32 (integral values)
    const float* W       = (const float*)d_in[1];   // [64][257] f32
    const int*   lut     = (const int*)d_in[2];     // [512] i32
    float*       out     = (float*)d_out;           // [N][64] f32
    (void)d_ws; (void)ws_size;

    const int n = in_sizes[0];                      // 2,097,152
    const int total_quads = n * (OUT_DIM / 4);      // 33,554,432

    onehot_purewrite_kernel<<<GRID, BLOCK, 0, stream>>>(
        raw_ids, W, lut, (f32x4*)out, total_quads);
}

// Round 10
// 102.348 us; speedup vs baseline: 1.2009x; 1.0296x over previous
//
#include <hip/hip_runtime.h>

// Problem constants (match reference)
#define DEPTH     257    // 256 train ids + OOV
#define OUT_DIM   64
#define OOV_B     256
#define LUT_SIZE  512
#define TAB_QUADS (DEPTH * 16)     // 4112 f32x4 = 65,792 B (bucket-space table)
#define BLOCK     1024
#define GRID      256              // 1 block/CU
#define STEPS     128              // steps per block: 8192 rows / 64 rows-per-step
#define ROWS_PER_BLK 8192          // contiguous slab per block (2 MB output)

typedef float f32x4 __attribute__((ext_vector_type(4)));

// R9 structure, ONE change: contiguous-slab output mapping. Block b owns
// rows [b*8192,(b+1)*8192) and walks its 2 MB slab SEQUENTIALLY (16 KB per
// step) instead of grid-strided 4 MB hops — per-CU monotone write stream,
// maximal DRAM page locality (the D2D-copy shape). Staging/LDS/store policy
// byte-identical to R9.
__global__ __launch_bounds__(BLOCK) void onehot_slab_kernel(
        const float* __restrict__ raw_ids,
        const float* __restrict__ W,
        const int* __restrict__ lut,
        f32x4* __restrict__ out4,
        int total_quads) {
    __shared__ f32x4 sTab[TAB_QUADS];        // 65,792 B
    __shared__ float sIds[ROWS_PER_BLK];     // 32,768 B
    __shared__ int   sLut[LUT_SIZE + 1];     //  2,052 B
    __shared__ int   sOk;

    if (threadIdx.x == 0) sOk = 1;
    __syncthreads();

    const int fastShape = (total_quads == GRID * ROWS_PER_BLK * 16);

    // ---- stage this block's contiguous id slab (32 KB, coalesced float4) ----
    if (fastShape) {
        const float4* raw4 = (const float4*)raw_ids;
        float4* sIds4 = (float4*)sIds;
        #pragma unroll
        for (int i = 0; i < 2; ++i) {
            int k = threadIdx.x + i * BLOCK;                 // 0..2047
            sIds4[k] = raw4[blockIdx.x * (ROWS_PER_BLK / 4) + k];
        }
    }
    // ---- stage lut + verify identity-min structure ----
    for (int k = threadIdx.x; k <= LUT_SIZE; k += BLOCK) {
        int v = (k < LUT_SIZE) ? lut[k] : OOV_B;
        sLut[k] = v;
        if (v != min(k, OOV_B)) sOk = 0;     // benign race: only 0 written
    }
    // ---- stage W.T bucket table (scalar L2 gathers, one-time) ----
    for (int k = threadIdx.x; k < TAB_QUADS; k += BLOCK) {
        int b  = k >> 4;                     // bucket 0..256
        int qq = k & 15;
        f32x4 v;
        v.x = W[(4 * qq + 0) * DEPTH + b];
        v.y = W[(4 * qq + 1) * DEPTH + b];
        v.z = W[(4 * qq + 2) * DEPTH + b];
        v.w = W[(4 * qq + 3) * DEPTH + b];
        sTab[k] = v;
    }
    __syncthreads();

    const bool fast = (sOk != 0);            // block-uniform
    const int q = threadIdx.x & 15;          // quad within row
    const int r = threadIdx.x >> 4;          // row-in-step 0..63

    if (fastShape && fast) {
        // Sequential slab walk: j advances +1024 quads (16 KB) per step.
        // Wave store = 4 consecutive rows = 1 KB contiguous; block step =
        // 64 rows = 16 KB contiguous; whole block = 2 MB monotone stream.
        int j = blockIdx.x * (ROWS_PER_BLK * 16) + threadIdx.x;
        #pragma unroll 1
        for (int m = 0; m < STEPS; m += 4, j += 4 * BLOCK) {
            float f0 = sIds[(m + 0) * 64 + r];
            float f1 = sIds[(m + 1) * 64 + r];
            float f2 = sIds[(m + 2) * 64 + r];
            float f3 = sIds[(m + 3) * 64 + r];
            unsigned u0 = min((unsigned)__float2int_rn(f0), (unsigned)OOV_B);
            unsigned u1 = min((unsigned)__float2int_rn(f1), (unsigned)OOV_B);
            unsigned u2 = min((unsigned)__float2int_rn(f2), (unsigned)OOV_B);
            unsigned u3 = min((unsigned)__float2int_rn(f3), (unsigned)OOV_B);
            f32x4 v0 = sTab[u0 * 16 + q];
            f32x4 v1 = sTab[u1 * 16 + q];
            f32x4 v2 = sTab[u2 * 16 + q];
            f32x4 v3 = sTab[u3 * 16 + q];
            out4[j]             = v0;
            out4[j + BLOCK]     = v1;
            out4[j + 2 * BLOCK] = v2;
            out4[j + 3 * BLOCK] = v3;
        }
    } else {
        // Generic path (any shape / any lut): ids from global, two-hop map.
        const int stride = GRID * BLOCK;
        for (int j = blockIdx.x * BLOCK + threadIdx.x; j < total_quads;
             j += stride) {
            unsigned i = min((unsigned)__float2int_rn(raw_ids[j >> 4]),
                             (unsigned)LUT_SIZE);
            unsigned b = min((unsigned)sLut[i], (unsigned)OOV_B);
            out4[j] = sTab[b * 16 + (j & 15)];
        }
    }
}

extern "C" void kernel_launch(void* const* d_in, const int* in_sizes, int n_in,
                              void* d_out, int out_size, void* d_ws,
                              size_t ws_size, hipStream_t stream) {
    const float* raw_ids = (const float*)d_in[0];   // [N] f32 (integral values)
    const float* W       = (const float*)d_in[1];   // [64][257] f32
    const int*   lut     = (const int*)d_in[2];     // [512] i32
    float*       out     = (float*)d_out;           // [N][64] f32
    (void)d_ws; (void)ws_size;

    const int n = in_sizes[0];                      // 2,097,152
    const int total_quads = n * (OUT_DIM / 4);      // 33,554,432

    onehot_slab_kernel<<<GRID, BLOCK, 0, stream>>>(
        raw_ids, W, lut, (f32x4*)out, total_quads);
}